// Round 9
// baseline (718.502 us; speedup 1.0000x reference)
//
#include <hip/hip_runtime.h>
#include <math.h>

#define T_LEN 1024
#define BATCH 1024
#define H 64
#define NB 4   // batches per block; 4x M-replication in the 16-row A tile

typedef __attribute__((ext_vector_type(4))) int   i32x4;

// ---- fast device math (v_exp_f32 / v_rcp_f32) ----
__device__ __forceinline__ float fast_rcp(float x) { return __builtin_amdgcn_rcpf(x); }
__device__ __forceinline__ float fast_sigmoid(float x) {
  return fast_rcp(1.0f + __expf(-x));
}
// tanh(x) = 1 - 2/(1+exp(2x)) — exact identity; saturates to ±1 at ±inf
// (exp->inf: rcp(inf)=0 -> 1; exp->0: 1-2 = -1). 5 inst vs 9 for the
// abs/copysign form it replaces.
__device__ __forceinline__ float fast_tanh(float x) {
  return fmaf(-2.0f, fast_rcp(1.0f + __expf(2.0f * x)), 1.0f);
}

// ===================== fused encoder + decoder =====================
// Grid 256 x 256thr: 1 block/CU, 4 waves. Block owns NB=4 batches; A-rows
// replicate each batch 4x so lane (q,l15) acc reg0 holds the complete
// i,f,g,o quadruple for its ONE cell (batch q, unit 16wv+l15).
//
// Gates GEMM in i8 double-digit fixed point (validated R7/R8, absmax 4.9e-4):
//   h = (a*128+b)*2^-13, W = (wa*128+wb)*2^-15
//   h.W = ((a.wa<<7) + a.wb + b.wa) * 2^-21  (b.wb ~3e-5, dropped; int-exact)
// 3 x mfma_i32_16x16x64_i8 per gate; digit partials combine in INTEGER
// (S=(P1<<7)+Pc < 2^25, cvt error <5e-7). h digits exchange through LDS as
// flat [bat][u] byte arrays (parity dbuf, one lgkm-only barrier/step).
//
// R9: decoder FUSED as a per-block tail — block's final h goes to LDS, then
// lane 0 of wave wv runs batch wv's scalar recurrence (hidden=1) and writes
// out columns directly. Kills the 2nd dispatch + inter-kernel gap + h_enc
// global round-trip; tails overlap across the 256 resident blocks.
__global__ __launch_bounds__(256, 1) void lstm_ae_kernel(
    const float* __restrict__ x,      // [T, BATCH]
    const float* __restrict__ Wih_e,  // [256, 1]
    const float* __restrict__ Whh_e,  // [256, 64]
    const float* __restrict__ bih_e,  // [256]
    const float* __restrict__ bhh_e,  // [256]
    const float* __restrict__ Wih_d,  // [4, 64]
    const float* __restrict__ Whh_d,  // [4, 1]
    const float* __restrict__ bih_d,  // [4]
    const float* __restrict__ bhh_d,  // [4]
    float* __restrict__ out)          // [T, BATCH]
{
  // [parity][digit][bat*H + u]
  __shared__ __align__(16) signed char dig[2][2][NB * H];   // 2 KB
  __shared__ float x_lds[T_LEN][NB];                        // 16 KB
  __shared__ float hdec[NB][H];                             // 1 KB

  const int tid  = threadIdx.x;
  const int lane = tid & 63;
  const int wv   = tid >> 6;        // n-tile group (0..3)
  const int q    = lane >> 4;
  const int l15  = lane & 15;
  const int b0   = blockIdx.x * NB;
  const int u    = wv * 16 + l15;   // this lane's hidden unit
  const int mb   = l15 >> 2;        // A-row batch (4x replication)
  const int bat  = q;               // this lane's cell batch (non-redundant)

  // ---- persistent weight digit fragments: 4 gates x {wa,wb}, 32 VGPRs ----
  i32x4 Ba[4], Bb[4];
  float wih_g[4], bias_g[4];
  for (int g = 0; g < 4; ++g) {
    const int n = g * 64 + u;       // gate row
    const float* wp = &Whh_e[n * H + q * 16];
    union { i32x4 v; signed char c[16]; } ua, ub;
#pragma unroll
    for (int j = 0; j < 16; ++j) {
      const int wint = (int)rintf(wp[j] * 32768.f);   // |.| <= 4096
      const int wa = (wint + 64) >> 7;                // [-32, 32]
      const int wb = wint - (wa << 7);                // [-64, 63]
      ua.c[j] = (signed char)wa;
      ub.c[j] = (signed char)wb;
    }
    Ba[g] = ua.v; Bb[g] = ub.v;
    wih_g[g]  = Wih_e[n];
    bias_g[g] = bih_e[n] + bhh_e[n];
  }

  // ---- one-time staging: x (float4 rows) + zero parity-0 digit buffers ----
  for (int t = tid; t < T_LEN; t += 256)
    *(float4*)&x_lds[t][0] = *(const float4*)&x[t * BATCH + b0];
  for (int i = tid; i < 2 * NB * H; i += 256)
    ((signed char*)dig[0])[i] = 0;      // h=0 -> both digits 0
  __syncthreads();

  float c = 0.0f, h_last = 0.0f;
  const i32x4 izero = {0, 0, 0, 0};

#define ENC_STEP(P, TT)                                                        \
  {                                                                            \
    const i32x4 Aa = *(const i32x4*)&dig[P][0][mb * H + q * 16];               \
    const i32x4 Ab = *(const i32x4*)&dig[P][1][mb * H + q * 16];               \
    const float xv = x_lds[TT][bat];                                           \
    float G[4];                                                                \
    _Pragma("unroll")                                                          \
    for (int g = 0; g < 4; ++g) {                                              \
      i32x4 P1 = __builtin_amdgcn_mfma_i32_16x16x64_i8(Aa, Ba[g], izero, 0, 0, 0); \
      i32x4 Pc = __builtin_amdgcn_mfma_i32_16x16x64_i8(Ab, Ba[g], izero, 0, 0, 0); \
      Pc = __builtin_amdgcn_mfma_i32_16x16x64_i8(Aa, Bb[g], Pc, 0, 0, 0);      \
      const int S = (P1[0] << 7) + Pc[0];      /* exact, < 2^25 */             \
      G[g] = fmaf((float)S, 0x1.0p-21f, fmaf(xv, wih_g[g], bias_g[g]));        \
    }                                                                          \
    const float iv = fast_sigmoid(G[0]);                                       \
    const float fv = fast_sigmoid(G[1]);                                       \
    const float gv = fast_tanh(G[2]);                                          \
    const float ov = fast_sigmoid(G[3]);                                       \
    c = fmaf(fv, c, iv * gv);                                                  \
    h_last = ov * fast_tanh(c);                                                \
    const int v  = (int)rintf(h_last * 8192.f);  /* [-8192, 8192] */           \
    const int ad = (v + 64) >> 7;                /* [-64, 64] */               \
    const int bd = v - (ad << 7);                /* [-64, 63] */               \
    dig[1 - (P)][0][bat * H + u] = (signed char)ad;                            \
    dig[1 - (P)][1][bat * H + u] = (signed char)bd;                            \
    __syncthreads();                                                           \
  }

  for (int t = 0; t < T_LEN; t += 2) {
    ENC_STEP(0, t)
    ENC_STEP(1, t + 1)
  }
#undef ENC_STEP

  // ---- decoder tail (fused): final h -> LDS, then 4 scalar chains ----
  hdec[bat][u] = h_last;
  __syncthreads();

  if (lane == 0) {
    // wave wv handles batch b0+wv; constant gate bases from h_enc = hdec[wv]
    float a0 = bih_d[0] + bhh_d[0];
    float a1 = bih_d[1] + bhh_d[1];
    float a2 = bih_d[2] + bhh_d[2];
    float a3 = bih_d[3] + bhh_d[3];
#pragma unroll 8
    for (int k = 0; k < H; ++k) {
      const float hv = hdec[wv][k];
      a0 = fmaf(Wih_d[0 * H + k], hv, a0);
      a1 = fmaf(Wih_d[1 * H + k], hv, a1);
      a2 = fmaf(Wih_d[2 * H + k], hv, a2);
      a3 = fmaf(Wih_d[3 * H + k], hv, a3);
    }
    const float w0 = Whh_d[0], w1 = Whh_d[1], w2 = Whh_d[2], w3 = Whh_d[3];

    float h = 0.0f, cd = 0.0f;
    float* outp = out + b0 + wv;
    for (int t = 0; t < T_LEN; ++t) {
      const float iv = fast_sigmoid(fmaf(w0, h, a0));
      const float fv = fast_sigmoid(fmaf(w1, h, a1));
      const float gv = fast_tanh(fmaf(w2, h, a2));
      const float ov = fast_sigmoid(fmaf(w3, h, a3));
      cd = fmaf(fv, cd, iv * gv);
      h = ov * fast_tanh(cd);
      outp[t * BATCH] = h;
    }
  }
}

extern "C" void kernel_launch(void* const* d_in, const int* in_sizes, int n_in,
                              void* d_out, int out_size, void* d_ws, size_t ws_size,
                              hipStream_t stream) {
  const float* x     = (const float*)d_in[0];
  const float* Wih_e = (const float*)d_in[1];
  const float* Whh_e = (const float*)d_in[2];
  const float* bih_e = (const float*)d_in[3];
  const float* bhh_e = (const float*)d_in[4];
  const float* Wih_d = (const float*)d_in[5];
  const float* Whh_d = (const float*)d_in[6];
  const float* bih_d = (const float*)d_in[7];
  const float* bhh_d = (const float*)d_in[8];
  float* out = (float*)d_out;

  lstm_ae_kernel<<<BATCH / NB, 256, 0, stream>>>(
      x, Wih_e, Whh_e, bih_e, bhh_e, Wih_d, Whh_d, bih_d, bhh_d, out);
}

// Round 10
// 716.399 us; speedup vs baseline: 1.0029x; 1.0029x over previous
//
#include <hip/hip_runtime.h>
#include <math.h>

#define T_LEN 1024
#define BATCH 1024
#define H 64
#define NB 4   // batches per block; 4x M-replication in the 16-row A tile

typedef __attribute__((ext_vector_type(4))) int   i32x4;

// ---- fast device math (v_exp_f32 / v_rcp_f32) ----
__device__ __forceinline__ float fast_rcp(float x) { return __builtin_amdgcn_rcpf(x); }
__device__ __forceinline__ float fast_sigmoid(float x) {
  return fast_rcp(1.0f + __expf(-x));
}
// tanh(x) = 1 - 2/(1+exp(2x)) — exact identity; saturates correctly.
__device__ __forceinline__ float fast_tanh(float x) {
  return fmaf(-2.0f, fast_rcp(1.0f + __expf(2.0f * x)), 1.0f);
}

// ===================== fused encoder + decoder =====================
// Encoder (validated R8, 362us): grid 256 x 256thr, 1 block/CU, NB=4 batches,
// 4x M-replication -> lane (q,l15) holds the complete i,f,g,o quadruple for
// its ONE cell (batch q, unit 16wv+l15). Gates GEMM in i8 double-digit fixed
// point: h=(a*128+b)*2^-13, W=(wa*128+wb)*2^-15, h.W=((a.wa<<7)+a.wb+b.wa)
// *2^-21 (b.wb dropped, ~3e-5). 3x mfma_i32_16x16x64_i8 per gate; digit
// partials combine exactly in integer. h digits exchange through LDS byte
// arrays, parity dbuf, one lgkm-only barrier/step.
//
// Decoder tail (R10 fix): R9 regressed 330us because the per-step scalar
// store held its source VGPR -> compiler serialized each step on the
// previous store's vmcnt retirement (~700 cyc store-ack chain). Now steps
// compute into an 8-deep register buffer and stores issue as a group: the
// reg-overwrite waitcnt reaches 8 stores (~1000 compute-cycles) back ->
// always retired, chain returns to its ~120 cyc/step compute floor.
// a-bases via full-wave butterfly reduce instead of 256 lane-0 loads.
__global__ __launch_bounds__(256, 1) void lstm_ae_kernel(
    const float* __restrict__ x,      // [T, BATCH]
    const float* __restrict__ Wih_e,  // [256, 1]
    const float* __restrict__ Whh_e,  // [256, 64]
    const float* __restrict__ bih_e,  // [256]
    const float* __restrict__ bhh_e,  // [256]
    const float* __restrict__ Wih_d,  // [4, 64]
    const float* __restrict__ Whh_d,  // [4, 1]
    const float* __restrict__ bih_d,  // [4]
    const float* __restrict__ bhh_d,  // [4]
    float* __restrict__ out)          // [T, BATCH]
{
  // [parity][digit][bat*H + u]
  __shared__ __align__(16) signed char dig[2][2][NB * H];   // 2 KB
  __shared__ float x_lds[T_LEN][NB];                        // 16 KB
  __shared__ float hdec[NB][H];                             // 1 KB

  const int tid  = threadIdx.x;
  const int lane = tid & 63;
  const int wv   = tid >> 6;        // n-tile group (0..3)
  const int q    = lane >> 4;
  const int l15  = lane & 15;
  const int b0   = blockIdx.x * NB;
  const int u    = wv * 16 + l15;   // this lane's hidden unit
  const int mb   = l15 >> 2;        // A-row batch (4x replication)
  const int bat  = q;               // this lane's cell batch (non-redundant)

  // ---- persistent weight digit fragments: 4 gates x {wa,wb}, 32 VGPRs ----
  i32x4 Ba[4], Bb[4];
  float wih_g[4], bias_g[4];
  for (int g = 0; g < 4; ++g) {
    const int n = g * 64 + u;       // gate row
    const float* wp = &Whh_e[n * H + q * 16];
    union { i32x4 v; signed char c[16]; } ua, ub;
#pragma unroll
    for (int j = 0; j < 16; ++j) {
      const int wint = (int)rintf(wp[j] * 32768.f);   // |.| <= 4096
      const int wa = (wint + 64) >> 7;                // [-32, 32]
      const int wb = wint - (wa << 7);                // [-64, 63]
      ua.c[j] = (signed char)wa;
      ub.c[j] = (signed char)wb;
    }
    Ba[g] = ua.v; Bb[g] = ub.v;
    wih_g[g]  = Wih_e[n];
    bias_g[g] = bih_e[n] + bhh_e[n];
  }

  // ---- one-time staging: x (float4 rows) + zero parity-0 digit buffers ----
  for (int t = tid; t < T_LEN; t += 256)
    *(float4*)&x_lds[t][0] = *(const float4*)&x[t * BATCH + b0];
  for (int i = tid; i < 2 * NB * H; i += 256)
    ((signed char*)dig[0])[i] = 0;      // h=0 -> both digits 0
  __syncthreads();

  float c = 0.0f, h_last = 0.0f;
  const i32x4 izero = {0, 0, 0, 0};

#define ENC_STEP(P, TT)                                                        \
  {                                                                            \
    const i32x4 Aa = *(const i32x4*)&dig[P][0][mb * H + q * 16];               \
    const i32x4 Ab = *(const i32x4*)&dig[P][1][mb * H + q * 16];               \
    const float xv = x_lds[TT][bat];                                           \
    float G[4];                                                                \
    _Pragma("unroll")                                                          \
    for (int g = 0; g < 4; ++g) {                                              \
      i32x4 P1 = __builtin_amdgcn_mfma_i32_16x16x64_i8(Aa, Ba[g], izero, 0, 0, 0); \
      i32x4 Pc = __builtin_amdgcn_mfma_i32_16x16x64_i8(Ab, Ba[g], izero, 0, 0, 0); \
      Pc = __builtin_amdgcn_mfma_i32_16x16x64_i8(Aa, Bb[g], Pc, 0, 0, 0);      \
      const int S = (P1[0] << 7) + Pc[0];      /* exact, < 2^25 */             \
      G[g] = fmaf((float)S, 0x1.0p-21f, fmaf(xv, wih_g[g], bias_g[g]));        \
    }                                                                          \
    const float iv = fast_sigmoid(G[0]);                                       \
    const float fv = fast_sigmoid(G[1]);                                       \
    const float gv = fast_tanh(G[2]);                                          \
    const float ov = fast_sigmoid(G[3]);                                       \
    c = fmaf(fv, c, iv * gv);                                                  \
    h_last = ov * fast_tanh(c);                                                \
    const int v  = (int)rintf(h_last * 8192.f);  /* [-8192, 8192] */           \
    const int ad = (v + 64) >> 7;                /* [-64, 64] */               \
    const int bd = v - (ad << 7);                /* [-64, 63] */               \
    dig[1 - (P)][0][bat * H + u] = (signed char)ad;                            \
    dig[1 - (P)][1][bat * H + u] = (signed char)bd;                            \
    __syncthreads();                                                           \
  }

  for (int t = 0; t < T_LEN; t += 2) {
    ENC_STEP(0, t)
    ENC_STEP(1, t + 1)
  }
#undef ENC_STEP

  // ---- decoder tail (fused): final h -> LDS ----
  hdec[bat][u] = h_last;
  __syncthreads();

  // a-bases via full-wave butterfly reduce: lane k contributes Wih_d[g][k]*h[k]
  const float hv = hdec[wv][lane];
  float p0 = Wih_d[0 * H + lane] * hv;
  float p1 = Wih_d[1 * H + lane] * hv;
  float p2 = Wih_d[2 * H + lane] * hv;
  float p3 = Wih_d[3 * H + lane] * hv;
#pragma unroll
  for (int off = 32; off > 0; off >>= 1) {
    p0 += __shfl_xor(p0, off, 64);
    p1 += __shfl_xor(p1, off, 64);
    p2 += __shfl_xor(p2, off, 64);
    p3 += __shfl_xor(p3, off, 64);
  }

  if (lane == 0) {
    const float a0 = p0 + bih_d[0] + bhh_d[0];
    const float a1 = p1 + bih_d[1] + bhh_d[1];
    const float a2 = p2 + bih_d[2] + bhh_d[2];
    const float a3 = p3 + bih_d[3] + bhh_d[3];
    const float w0 = Whh_d[0], w1 = Whh_d[1], w2 = Whh_d[2], w3 = Whh_d[3];

    float h = 0.0f, cd = 0.0f;
    float* outp = out + b0 + wv;      // wave wv owns batch b0+wv
    for (int t = 0; t < T_LEN; t += 8) {
      float buf[8];
#pragma unroll
      for (int uu = 0; uu < 8; ++uu) {
        const float iv = fast_sigmoid(fmaf(w0, h, a0));
        const float fv = fast_sigmoid(fmaf(w1, h, a1));
        const float gv = fast_tanh(fmaf(w2, h, a2));
        const float ov = fast_sigmoid(fmaf(w3, h, a3));
        cd = fmaf(fv, cd, iv * gv);
        h = ov * fast_tanh(cd);
        buf[uu] = h;
      }
      // grouped stores: reg-overwrite waitcnt now reaches 8 stores back
#pragma unroll
      for (int uu = 0; uu < 8; ++uu)
        outp[(t + uu) * BATCH] = buf[uu];
    }
  }
}

extern "C" void kernel_launch(void* const* d_in, const int* in_sizes, int n_in,
                              void* d_out, int out_size, void* d_ws, size_t ws_size,
                              hipStream_t stream) {
  const float* x     = (const float*)d_in[0];
  const float* Wih_e = (const float*)d_in[1];
  const float* Whh_e = (const float*)d_in[2];
  const float* bih_e = (const float*)d_in[3];
  const float* bhh_e = (const float*)d_in[4];
  const float* Wih_d = (const float*)d_in[5];
  const float* Whh_d = (const float*)d_in[6];
  const float* bih_d = (const float*)d_in[7];
  const float* bhh_d = (const float*)d_in[8];
  float* out = (float*)d_out;

  lstm_ae_kernel<<<BATCH / NB, 256, 0, stream>>>(
      x, Wih_e, Whh_e, bih_e, bhh_e, Wih_d, Whh_d, bih_d, bhh_d, out);
}

// Round 11
// 707.747 us; speedup vs baseline: 1.0152x; 1.0122x over previous
//
#include <hip/hip_runtime.h>
#include <math.h>

#define T_LEN 1024
#define BATCH 1024
#define H 64
#define NB 4   // batches per block; 4x M-replication in the 16-row A tile

typedef __attribute__((ext_vector_type(4))) int   i32x4;

// ---- fast device math (v_exp_f32 / v_rcp_f32) ----
__device__ __forceinline__ float fast_rcp(float x) { return __builtin_amdgcn_rcpf(x); }
__device__ __forceinline__ float fast_sigmoid(float x) {
  return fast_rcp(1.0f + __expf(-x));
}
// tanh(x) = 1 - 2/(1+exp(2x)) — exact identity; saturates correctly.
__device__ __forceinline__ float fast_tanh(float x) {
  return fmaf(-2.0f, fast_rcp(1.0f + __expf(2.0f * x)), 1.0f);
}

// ===================== fused encoder + decoder =====================
// Encoder (validated R8, 362us): grid 256 x 256thr, 1 block/CU, NB=4 batches,
// 4x M-replication -> lane (q,l15) holds the complete i,f,g,o quadruple for
// its ONE cell (batch q, unit 16wv+l15). Gates GEMM in i8 double-digit fixed
// point: h=(a*128+b)*2^-13, W=(wa*128+wb)*2^-15, h.W=((a.wa<<7)+a.wb+b.wa)
// *2^-21 (b.wb dropped, ~3e-5). 3x mfma_i32_16x16x64_i8 per gate; digit
// partials combine exactly in integer. h digits exchange through LDS byte
// arrays, parity dbuf, one lgkm-only barrier/step.
//
// Decoder tail (R11): R9/R10 showed ~750 cyc/step regardless of source-level
// store grouping — hypothesis: the compiler serializes the chain on global
// store retirement no matter how stores are grouped. DECISIVE TEST: the chain
// now writes h to an LDS stage (ds_write retires ~20 cyc; never stalls), and
// global stores happen in a cooperative float4 epilogue AFTER the chains.
// If store-retirement was the cost, tail collapses to the chain's compute
// floor; if not, the chain itself is ~700 cyc/step (trans-latency evidence).
__global__ __launch_bounds__(256, 1) void lstm_ae_kernel(
    const float* __restrict__ x,      // [T, BATCH]
    const float* __restrict__ Wih_e,  // [256, 1]
    const float* __restrict__ Whh_e,  // [256, 64]
    const float* __restrict__ bih_e,  // [256]
    const float* __restrict__ bhh_e,  // [256]
    const float* __restrict__ Wih_d,  // [4, 64]
    const float* __restrict__ Whh_d,  // [4, 1]
    const float* __restrict__ bih_d,  // [4]
    const float* __restrict__ bhh_d,  // [4]
    float* __restrict__ out)          // [T, BATCH]
{
  // [parity][digit][bat*H + u]
  __shared__ __align__(16) signed char dig[2][2][NB * H];   // 2 KB
  __shared__ float x_lds[T_LEN * NB];                       // 16 KB (reused as decoder stage)
  __shared__ float hdec[NB][H];                             // 1 KB

  const int tid  = threadIdx.x;
  const int lane = tid & 63;
  const int wv   = tid >> 6;        // n-tile group (0..3)
  const int q    = lane >> 4;
  const int l15  = lane & 15;
  const int b0   = blockIdx.x * NB;
  const int u    = wv * 16 + l15;   // this lane's hidden unit
  const int mb   = l15 >> 2;        // A-row batch (4x replication)
  const int bat  = q;               // this lane's cell batch (non-redundant)

  // ---- persistent weight digit fragments: 4 gates x {wa,wb}, 32 VGPRs ----
  i32x4 Ba[4], Bb[4];
  float wih_g[4], bias_g[4];
  for (int g = 0; g < 4; ++g) {
    const int n = g * 64 + u;       // gate row
    const float* wp = &Whh_e[n * H + q * 16];
    union { i32x4 v; signed char c[16]; } ua, ub;
#pragma unroll
    for (int j = 0; j < 16; ++j) {
      const int wint = (int)rintf(wp[j] * 32768.f);   // |.| <= 4096
      const int wa = (wint + 64) >> 7;                // [-32, 32]
      const int wb = wint - (wa << 7);                // [-64, 63]
      ua.c[j] = (signed char)wa;
      ub.c[j] = (signed char)wb;
    }
    Ba[g] = ua.v; Bb[g] = ub.v;
    wih_g[g]  = Wih_e[n];
    bias_g[g] = bih_e[n] + bhh_e[n];
  }

  // ---- one-time staging: x (float4 rows, layout [t][b]) + zero digits ----
  for (int t = tid; t < T_LEN; t += 256)
    *(float4*)&x_lds[t * NB] = *(const float4*)&x[t * BATCH + b0];
  for (int i = tid; i < 2 * NB * H; i += 256)
    ((signed char*)dig[0])[i] = 0;      // h=0 -> both digits 0
  __syncthreads();

  float c = 0.0f, h_last = 0.0f;
  const i32x4 izero = {0, 0, 0, 0};

#define ENC_STEP(P, TT)                                                        \
  {                                                                            \
    const i32x4 Aa = *(const i32x4*)&dig[P][0][mb * H + q * 16];               \
    const i32x4 Ab = *(const i32x4*)&dig[P][1][mb * H + q * 16];               \
    const float xv = x_lds[(TT) * NB + bat];                                   \
    float G[4];                                                                \
    _Pragma("unroll")                                                          \
    for (int g = 0; g < 4; ++g) {                                              \
      i32x4 P1 = __builtin_amdgcn_mfma_i32_16x16x64_i8(Aa, Ba[g], izero, 0, 0, 0); \
      i32x4 Pc = __builtin_amdgcn_mfma_i32_16x16x64_i8(Ab, Ba[g], izero, 0, 0, 0); \
      Pc = __builtin_amdgcn_mfma_i32_16x16x64_i8(Aa, Bb[g], Pc, 0, 0, 0);      \
      const int S = (P1[0] << 7) + Pc[0];      /* exact, < 2^25 */             \
      G[g] = fmaf((float)S, 0x1.0p-21f, fmaf(xv, wih_g[g], bias_g[g]));        \
    }                                                                          \
    const float iv = fast_sigmoid(G[0]);                                       \
    const float fv = fast_sigmoid(G[1]);                                       \
    const float gv = fast_tanh(G[2]);                                          \
    const float ov = fast_sigmoid(G[3]);                                       \
    c = fmaf(fv, c, iv * gv);                                                  \
    h_last = ov * fast_tanh(c);                                                \
    const int v  = (int)rintf(h_last * 8192.f);  /* [-8192, 8192] */           \
    const int ad = (v + 64) >> 7;                /* [-64, 64] */               \
    const int bd = v - (ad << 7);                /* [-64, 63] */               \
    dig[1 - (P)][0][bat * H + u] = (signed char)ad;                            \
    dig[1 - (P)][1][bat * H + u] = (signed char)bd;                            \
    __syncthreads();                                                           \
  }

  for (int t = 0; t < T_LEN; t += 2) {
    ENC_STEP(0, t)
    ENC_STEP(1, t + 1)
  }
#undef ENC_STEP

  // ---- decoder tail: final h -> LDS ----
  hdec[bat][u] = h_last;
  __syncthreads();

  // a-bases via full-wave butterfly reduce: lane k contributes Wih_d[g][k]*h[k]
  const float hv = hdec[wv][lane];
  float p0 = Wih_d[0 * H + lane] * hv;
  float p1 = Wih_d[1 * H + lane] * hv;
  float p2 = Wih_d[2 * H + lane] * hv;
  float p3 = Wih_d[3 * H + lane] * hv;
#pragma unroll
  for (int off = 32; off > 0; off >>= 1) {
    p0 += __shfl_xor(p0, off, 64);
    p1 += __shfl_xor(p1, off, 64);
    p2 += __shfl_xor(p2, off, 64);
    p3 += __shfl_xor(p3, off, 64);
  }

  // stage[t*4 + wv] reuses x_lds (dead after encoder; barrier above orders it)
  float* stage = x_lds;
  if (lane == 0) {
    const float a0 = p0 + bih_d[0] + bhh_d[0];
    const float a1 = p1 + bih_d[1] + bhh_d[1];
    const float a2 = p2 + bih_d[2] + bhh_d[2];
    const float a3 = p3 + bih_d[3] + bhh_d[3];
    const float w0 = Whh_d[0], w1 = Whh_d[1], w2 = Whh_d[2], w3 = Whh_d[3];

    float h = 0.0f, cd = 0.0f;
    for (int t = 0; t < T_LEN; ++t) {
      const float iv = fast_sigmoid(fmaf(w0, h, a0));
      const float fv = fast_sigmoid(fmaf(w1, h, a1));
      const float gv = fast_tanh(fmaf(w2, h, a2));
      const float ov = fast_sigmoid(fmaf(w3, h, a3));
      cd = fmaf(fv, cd, iv * gv);
      h = ov * fast_tanh(cd);
      stage[t * 4 + wv] = h;   // ds_write: retires in ~20 cyc, never stalls chain
    }
  }
  __syncthreads();

  // cooperative epilogue: row t = 16 B contiguous in out -> one dwordx4/row
  for (int t = tid; t < T_LEN; t += 256) {
    const float4 v = *(const float4*)&stage[t * 4];
    *(float4*)&out[t * BATCH + b0] = v;
  }
}

extern "C" void kernel_launch(void* const* d_in, const int* in_sizes, int n_in,
                              void* d_out, int out_size, void* d_ws, size_t ws_size,
                              hipStream_t stream) {
  const float* x     = (const float*)d_in[0];
  const float* Wih_e = (const float*)d_in[1];
  const float* Whh_e = (const float*)d_in[2];
  const float* bih_e = (const float*)d_in[3];
  const float* bhh_e = (const float*)d_in[4];
  const float* Wih_d = (const float*)d_in[5];
  const float* Whh_d = (const float*)d_in[6];
  const float* bih_d = (const float*)d_in[7];
  const float* bhh_d = (const float*)d_in[8];
  float* out = (float*)d_out;

  lstm_ae_kernel<<<BATCH / NB, 256, 0, stream>>>(
      x, Wih_e, Whh_e, bih_e, bhh_e, Wih_d, Whh_d, bih_d, bhh_d, out);
}

// Round 12
// 470.780 us; speedup vs baseline: 1.5262x; 1.5033x over previous
//
#include <hip/hip_runtime.h>
#include <math.h>

#define T_LEN 1024
#define BATCH 1024
#define H 64
#define NB 4   // batches per block; 4x M-replication in the 16-row A tile

typedef __attribute__((ext_vector_type(4))) int   i32x4;

// ---- fast device math (v_exp_f32 / v_rcp_f32) ----
__device__ __forceinline__ float fast_rcp(float x) { return __builtin_amdgcn_rcpf(x); }
__device__ __forceinline__ float fast_sigmoid(float x) {
  return fast_rcp(1.0f + __expf(-x));
}
// sigmoid with pre-negated argument: sigmoid(x) where nx = -x is given
__device__ __forceinline__ float fast_sigmoid_n(float nx) {
  return fast_rcp(1.0f + __expf(nx));
}
// tanh(x) = 1 - 2/(1+exp(2x)) — exact identity; saturates correctly.
__device__ __forceinline__ float fast_tanh(float x) {
  return fmaf(-2.0f, fast_rcp(1.0f + __expf(2.0f * x)), 1.0f);
}

// ===================== encoder =====================
// (validated R8/R11, ~362us): grid 256 x 256thr, 1 block/CU, NB=4 batches,
// 4x M-replication -> lane (q,l15) holds the complete i,f,g,o quadruple for
// its ONE cell (batch q, unit 16wv+l15). Gates GEMM in i8 double-digit fixed
// point: h=(a*128+b)*2^-13, W=(wa*128+wb)*2^-15, h.W=((a.wa<<7)+a.wb+b.wa)
// *2^-21 (b.wb dropped, ~3e-5). 3x mfma_i32_16x16x64_i8 per gate; digit
// partials combine exactly in integer. h digits exchange through LDS byte
// arrays, parity dbuf, one lgkm-only barrier/step.
// R9-R11 lesson: decoder fusion as per-block lane-0 tails costs ~720 cyc/step
// vs ~280 for the wide standalone decoder — encoder stays decoder-free.
__global__ __launch_bounds__(256, 1) void encoder_kernel(
    const float* __restrict__ x,      // [T, BATCH]
    const float* __restrict__ Wih_e,  // [256, 1]
    const float* __restrict__ Whh_e,  // [256, 64]
    const float* __restrict__ bih_e,  // [256]
    const float* __restrict__ bhh_e,  // [256]
    float* __restrict__ h_enc)        // [BATCH, 64]
{
  // [parity][digit][bat*H + u]
  __shared__ __align__(16) signed char dig[2][2][NB * H];   // 2 KB
  __shared__ float x_lds[T_LEN * NB];                       // 16 KB

  const int tid  = threadIdx.x;
  const int lane = tid & 63;
  const int wv   = tid >> 6;        // n-tile group (0..3)
  const int q    = lane >> 4;
  const int l15  = lane & 15;
  const int b0   = blockIdx.x * NB;
  const int u    = wv * 16 + l15;   // this lane's hidden unit
  const int mb   = l15 >> 2;        // A-row batch (4x replication)
  const int bat  = q;               // this lane's cell batch (non-redundant)

  // ---- persistent weight digit fragments: 4 gates x {wa,wb}, 32 VGPRs ----
  i32x4 Ba[4], Bb[4];
  float wih_g[4], bias_g[4];
  for (int g = 0; g < 4; ++g) {
    const int n = g * 64 + u;       // gate row
    const float* wp = &Whh_e[n * H + q * 16];
    union { i32x4 v; signed char c[16]; } ua, ub;
#pragma unroll
    for (int j = 0; j < 16; ++j) {
      const int wint = (int)rintf(wp[j] * 32768.f);   // |.| <= 4096
      const int wa = (wint + 64) >> 7;                // [-32, 32]
      const int wb = wint - (wa << 7);                // [-64, 63]
      ua.c[j] = (signed char)wa;
      ub.c[j] = (signed char)wb;
    }
    Ba[g] = ua.v; Bb[g] = ub.v;
    wih_g[g]  = Wih_e[n];
    bias_g[g] = bih_e[n] + bhh_e[n];
  }

  // ---- one-time staging: x (float4 rows, layout [t][b]) + zero digits ----
  for (int t = tid; t < T_LEN; t += 256)
    *(float4*)&x_lds[t * NB] = *(const float4*)&x[t * BATCH + b0];
  for (int i = tid; i < 2 * NB * H; i += 256)
    ((signed char*)dig[0])[i] = 0;      // h=0 -> both digits 0
  __syncthreads();

  float c = 0.0f, h_last = 0.0f;
  const i32x4 izero = {0, 0, 0, 0};

#define ENC_STEP(P, TT)                                                        \
  {                                                                            \
    const i32x4 Aa = *(const i32x4*)&dig[P][0][mb * H + q * 16];               \
    const i32x4 Ab = *(const i32x4*)&dig[P][1][mb * H + q * 16];               \
    const float xv = x_lds[(TT) * NB + bat];                                   \
    float G[4];                                                                \
    _Pragma("unroll")                                                          \
    for (int g = 0; g < 4; ++g) {                                              \
      i32x4 P1 = __builtin_amdgcn_mfma_i32_16x16x64_i8(Aa, Ba[g], izero, 0, 0, 0); \
      i32x4 Pc = __builtin_amdgcn_mfma_i32_16x16x64_i8(Ab, Ba[g], izero, 0, 0, 0); \
      Pc = __builtin_amdgcn_mfma_i32_16x16x64_i8(Aa, Bb[g], Pc, 0, 0, 0);      \
      const int S = (P1[0] << 7) + Pc[0];      /* exact, < 2^25 */             \
      G[g] = fmaf((float)S, 0x1.0p-21f, fmaf(xv, wih_g[g], bias_g[g]));        \
    }                                                                          \
    const float iv = fast_sigmoid(G[0]);                                       \
    const float fv = fast_sigmoid(G[1]);                                       \
    const float gv = fast_tanh(G[2]);                                          \
    const float ov = fast_sigmoid(G[3]);                                       \
    c = fmaf(fv, c, iv * gv);                                                  \
    h_last = ov * fast_tanh(c);                                                \
    const int v  = (int)rintf(h_last * 8192.f);  /* [-8192, 8192] */           \
    const int ad = (v + 64) >> 7;                /* [-64, 64] */               \
    const int bd = v - (ad << 7);                /* [-64, 63] */               \
    dig[1 - (P)][0][bat * H + u] = (signed char)ad;                            \
    dig[1 - (P)][1][bat * H + u] = (signed char)bd;                            \
    __syncthreads();                                                           \
  }

  for (int t = 0; t < T_LEN; t += 2) {
    ENC_STEP(0, t)
    ENC_STEP(1, t + 1)
  }
#undef ENC_STEP

  h_enc[(b0 + bat) * H + u] = h_last;
}

// ===================== decoder =====================
// Wide form (R8-validated structure): one lane per batch, 16 waves, grid 16.
// R12 fixes: (a) 8-deep register store buffer -> coalesced stores issue as a
// group, reg-overwrite waitcnt reaches 8 stores back (vmcnt window) instead
// of serializing each step on store retirement; (b) short tanh identity;
// (c) sigmoid args pre-negated (fold -x into constants).
__global__ __launch_bounds__(64) void decoder_kernel(
    const float* __restrict__ h_enc,  // [BATCH, 64]
    const float* __restrict__ Wih,    // [4, 64]
    const float* __restrict__ Whh,    // [4, 1]
    const float* __restrict__ bih,    // [4]
    const float* __restrict__ bhh,    // [4]
    float* __restrict__ out)          // [T, BATCH]
{
  const int b = blockIdx.x * blockDim.x + threadIdx.x;

  // gate bases (negated for i,f,o: sigmoid uses exp(+narg))
  float a0 = bih[0] + bhh[0];
  float a1 = bih[1] + bhh[1];
  float a2 = bih[2] + bhh[2];
  float a3 = bih[3] + bhh[3];
#pragma unroll 8
  for (int k = 0; k < H; ++k) {
    const float hv = h_enc[b * H + k];
    a0 = fmaf(Wih[0 * H + k], hv, a0);
    a1 = fmaf(Wih[1 * H + k], hv, a1);
    a2 = fmaf(Wih[2 * H + k], hv, a2);
    a3 = fmaf(Wih[3 * H + k], hv, a3);
  }
  const float w0 = Whh[0], w1 = Whh[1], w2 = Whh[2], w3 = Whh[3];
  const float na0 = -a0, nw0 = -w0;   // i gate, negated
  const float na1 = -a1, nw1 = -w1;   // f gate, negated
  const float na3 = -a3, nw3 = -w3;   // o gate, negated

  float h = 0.0f, c = 0.0f;
  float* outp = out + b;
  for (int t = 0; t < T_LEN; t += 8) {
    float buf[8];
#pragma unroll
    for (int uu = 0; uu < 8; ++uu) {
      const float iv = fast_sigmoid_n(fmaf(nw0, h, na0));
      const float fv = fast_sigmoid_n(fmaf(nw1, h, na1));
      const float gv = fast_tanh(fmaf(w2, h, a2));
      const float ov = fast_sigmoid_n(fmaf(nw3, h, na3));
      c = fmaf(fv, c, iv * gv);
      h = ov * fast_tanh(c);
      buf[uu] = h;
    }
    // grouped coalesced stores: 8 vmcnt items in flight, no per-step stall
#pragma unroll
    for (int uu = 0; uu < 8; ++uu)
      outp[(t + uu) * BATCH] = buf[uu];
  }
}

extern "C" void kernel_launch(void* const* d_in, const int* in_sizes, int n_in,
                              void* d_out, int out_size, void* d_ws, size_t ws_size,
                              hipStream_t stream) {
  const float* x     = (const float*)d_in[0];
  const float* Wih_e = (const float*)d_in[1];
  const float* Whh_e = (const float*)d_in[2];
  const float* bih_e = (const float*)d_in[3];
  const float* bhh_e = (const float*)d_in[4];
  const float* Wih_d = (const float*)d_in[5];
  const float* Whh_d = (const float*)d_in[6];
  const float* bih_d = (const float*)d_in[7];
  const float* bhh_d = (const float*)d_in[8];
  float* out = (float*)d_out;

  float* h_enc = (float*)d_ws;  // 1024*64*4 = 256 KB scratch

  encoder_kernel<<<BATCH / NB, 256, 0, stream>>>(x, Wih_e, Whh_e, bih_e, bhh_e, h_enc);
  decoder_kernel<<<BATCH / 64, 64, 0, stream>>>(h_enc, Wih_d, Whh_d, bih_d, bhh_d, out);
}